// Round 13
// baseline (137.699 us; speedup 1.0000x reference)
//
#include <hip/hip_runtime.h>
#include <math.h>

typedef unsigned short u16;
typedef unsigned long long u64;
typedef __attribute__((ext_vector_type(8))) short bf16x8;
typedef __attribute__((ext_vector_type(4))) float f32x4;

__device__ __forceinline__ float sigf(float x)  { return 1.0f / (1.0f + __expf(-x)); }
__device__ __forceinline__ float tanhf_(float x){ float e = __expf(2.0f * x); return 1.0f - 2.0f / (e + 1.0f); }
__device__ __forceinline__ u16 f2bf(float f) {
    unsigned x = __float_as_uint(f);
    return (u16)((x + 0x7fffu + ((x >> 16) & 1u)) >> 16);
}

// u64-key sorted insert: keys k0<=k1<=k2<=k3, key = (asuint(d2)<<24)|idx.
// (d2,idx) order == np's (dist,idx) order — verified bit-identical r14/r0/r1/r4/r5/r6/r9/r10/r12.
#define INSU(KEY) do {                                                              \
    u64 _k = (KEY);                                                                 \
    k3 = (_k < k3) ? _k : k3;                                                       \
    { bool _c = k3 < k2; u64 _lo = _c ? k3 : k2, _hi = _c ? k2 : k3; k2 = _lo; k3 = _hi; } \
    { bool _c = k2 < k1; u64 _lo = _c ? k2 : k1, _hi = _c ? k1 : k2; k1 = _lo; k2 = _hi; } \
    { bool _c = k1 < k0; u64 _lo = _c ? k1 : k0, _hi = _c ? k0 : k1; k0 = _lo; k1 = _hi; } \
} while (0)

// merge two ascending sorted-4 float lists, keep lowest 4 sorted in X (bitonic).
// (hardware-proven r1/r4/r5/r6/r9/r10/r12)
#define MRG4(X0,X1,X2,X3,Y0,Y1,Y2,Y3) do {                                          \
    float _q0 = fminf((X0),(Y3));                                                   \
    float _q1 = fminf((X1),(Y2));                                                   \
    float _q2 = fminf((X2),(Y1));                                                   \
    float _q3 = fminf((X3),(Y0));                                                   \
    float _l0 = fminf(_q0,_q2), _h0 = fmaxf(_q0,_q2);                               \
    float _l1 = fminf(_q1,_q3), _h1 = fmaxf(_q1,_q3);                               \
    (X0) = fminf(_l0,_l1); (X1) = fmaxf(_l0,_l1);                                   \
    (X2) = fminf(_h0,_h1); (X3) = fmaxf(_h0,_h1);                                   \
} while (0)

#define INS4(D, J) do {                                                              \
    float _d = (D); int _j = (J);                                                    \
    if (_d < bd3 || (_d == bd3 && _j < bj3)) {                                       \
        bd3 = _d; bj3 = _j;                                                          \
        if (bd3 < bd2 || (bd3 == bd2 && bj3 < bj2)) {                                \
            float _t = bd2; bd2 = bd3; bd3 = _t; int _u = bj2; bj2 = bj3; bj3 = _u; }\
        if (bd2 < bd1 || (bd2 == bd1 && bj2 < bj1)) {                                \
            float _t = bd1; bd1 = bd2; bd2 = _t; int _u = bj1; bj1 = bj2; bj2 = _u; }\
        if (bd1 < bd0 || (bd1 == bd0 && bj1 < bj0)) {                                \
            float _t = bd0; bd0 = bd1; bd1 = _t; int _u = bj0; bj0 = bj1; bj1 = _u; }\
    } } while (0)

__global__ void diag_kernel(float* out, int code, int out_size) {
    if (out_size > 0) out[0] = (float)code * 1.0e8f;
}

// prep: same (g,k)->Wgf/Wpf mapping as all passing rounds; loads as 2x float4
// (condition uniform per thread; values byte-identical). Passed r6/r9/r10/r12.
__device__ __forceinline__ void prep_item(
    int id, const float* Wih, const float* Whh, const float* Wp,
    u16* Wgf, u16* Wpf)
{
    if (id < 36864) {                        // gates: 64 gt * 9 kt * 64 lanes
        int gt = id / 576, rem = id - gt * 576;
        int kt = rem >> 6, ln = rem & 63;
        int g  = gt * 16 + (ln & 15);
        int k  = kt * 32 + (ln >> 4) * 8;
        u16* dst = Wgf + (size_t)id * 8;
        const float* src = (k < 32) ? (Wih + (size_t)g * 32 + k)
                                    : (Whh + (size_t)g * 256 + (k - 32));
        float4 v0 = ((const float4*)src)[0];
        float4 v1 = ((const float4*)src)[1];
        dst[0] = f2bf(v0.x); dst[1] = f2bf(v0.y); dst[2] = f2bf(v0.z); dst[3] = f2bf(v0.w);
        dst[4] = f2bf(v1.x); dst[5] = f2bf(v1.y); dst[6] = f2bf(v1.z); dst[7] = f2bf(v1.w);
    } else if (id < 37888) {                 // pool: 2 pt * 8 kt * 64 lanes
        int id2 = id - 36864;
        int pt = id2 >> 9, rem = id2 & 511;
        int kt = rem >> 6, ln = rem & 63;
        int o  = pt * 16 + (ln & 15);
        int k  = kt * 32 + (ln >> 4) * 8;
        u16* dst = Wpf + (size_t)id2 * 8;
        const float* src = Wp + (size_t)o * 256 + k;
        float4 v0 = ((const float4*)src)[0];
        float4 v1 = ((const float4*)src)[1];
        dst[0] = f2bf(v0.x); dst[1] = f2bf(v0.y); dst[2] = f2bf(v0.z); dst[3] = f2bf(v0.w);
        dst[4] = f2bf(v1.x); dst[5] = f2bf(v1.y); dst[6] = f2bf(v1.z); dst[7] = f2bf(v1.w);
    }
}

// K1-LDS (r13): r10's HW-passed two-phase selection with TWO WAVES PER PED.
// Diagnosis: K1 stuck at ~36us while aggregate VALU(~14us)+LDS(~6us) say ~20 —
// ~60% is per-wave serial-chain stall at only 4 waves/SIMD (48KB LDS -> 2
// blocks/CU x 8 waves). Fix: 1024-thread blocks, 16 waves, still 8 peds ->
// 2 blocks/CU x 16 waves = 32 waves/CU (8/SIMD, 2x latency hiding) AND each
// wave scans only HALF the pair-range (serial chains halve). Cross-wave glue:
//   thr: each wave's MRG4 butterfly top-4 of its 64 lane-mins -> LDS exchange
//        -> MRG4 with partner -> thr = 4th-smallest of 128 lane-mins
//        (subset-order-stat >= exact 4th, same proof as r5-r12 => all true
//        top-4 pass phase 2's filter; filter is pure optimization).
//   keys: per-wave filtered-INSU + u64 butterfly -> LDS -> half-0 INSUs the
//        partner's 4 keys (order-independent) -> epilogue.
// No early return before barriers: invalid peds clamp i and mask final writes.
__global__ __launch_bounds__(1024, 8) void knn_prep_lds_kernel(
    const float* __restrict__ obs1, const float* __restrict__ obs2,
    const float* __restrict__ Wemb, const float* __restrict__ bemb,
    const float* __restrict__ Wih,  const float* __restrict__ Whh,
    const float* __restrict__ Wp,
    u16* __restrict__ Wgf, u16* __restrict__ Wpf,
    int n, int knn_blocks, float* __restrict__ out)
{
    extern __shared__ __align__(16) char smem[];

    const int t = threadIdx.x;                // 0..1023

    if (blockIdx.x >= knn_blocks) {           // whole block -> prep (no barriers run)
        int id = (blockIdx.x - knn_blocks) * 1024 + t;
        prep_item(id, Wih, Whh, Wp, Wgf, Wpf);
        return;
    }

    float4* s4 = (float4*)smem;               // [n2] staged obs2 pairs
    float2* sP = (float2*)smem;               // float2 view (odd tail)
    const int n2 = n >> 1;                    // point-pairs
    const size_t ns = (size_t)((n + 1) & ~1) * 8;
    float* sTh = (float*)(smem + ns);         // [8 peds][2 halves][4] floats (256 B)
    u64*   sKy = (u64*)(smem + ns + 256);     // [8 peds][2 halves][4] u64   (512 B)

    const float FINF = __int_as_float(0x7f800000);
    const float2* o2 = (const float2*)obs2;
    const float4* o4 = (const float4*)obs2;

    // ---- stage obs2 -> LDS, coalesced float4 (r4/r10-proven pattern) ----
    for (int idx = t; idx < n2; idx += 1024) s4[idx] = o4[idx];
    if ((n & 1) && t == 0) sP[n - 1] = o2[n - 1];
    __syncthreads();                          // all 1024 threads reach

    const int lane = t & 63;
    const int w    = t >> 6;                  // 0..15
    const int g    = w & 7;                   // ped slot within block
    const int half = w >> 3;                  // 0/1: which half of pair-space
    const int iraw = blockIdx.x * 8 + g;
    const int i    = (iraw < n) ? iraw : (n - 1);   // clamp; writes masked later
    const float2 pi = o2[i];

    // ---------- phase 1: lane-min scan over this wave's half ----------
    float mm0 = FINF, mm1 = FINF, mm2 = FINF, mm3 = FINF;

    int f = lane + (half << 6);
    for (; f + 128 < n2; f += 256) {          // 2 ds_read_b128 in flight
        float4 pa = s4[f], pb = s4[f + 128];
        int j0 = 2 * f;
        float dxa = pa.x - pi.x, dya = pa.y - pi.y;
        float da = __fadd_rn(__fmul_rn(dxa, dxa), __fmul_rn(dya, dya));
        da = (j0 == i) ? FINF : da;
        float dxb = pa.z - pi.x, dyb = pa.w - pi.y;
        float db = __fadd_rn(__fmul_rn(dxb, dxb), __fmul_rn(dyb, dyb));
        db = (j0 + 1 == i) ? FINF : db;
        mm0 = fminf(mm0, da); mm1 = fminf(mm1, db);
        int j1 = 2 * (f + 128);
        float dxc = pb.x - pi.x, dyc = pb.y - pi.y;
        float dc = __fadd_rn(__fmul_rn(dxc, dxc), __fmul_rn(dyc, dyc));
        dc = (j1 == i) ? FINF : dc;
        float dxd = pb.z - pi.x, dyd = pb.w - pi.y;
        float dd = __fadd_rn(__fmul_rn(dxd, dxd), __fmul_rn(dyd, dyd));
        dd = (j1 + 1 == i) ? FINF : dd;
        mm2 = fminf(mm2, dc); mm3 = fminf(mm3, dd);
    }
    for (; f < n2; f += 128) {
        float4 pa = s4[f];
        int j0 = 2 * f;
        float dxa = pa.x - pi.x, dya = pa.y - pi.y;
        float da = __fadd_rn(__fmul_rn(dxa, dxa), __fmul_rn(dya, dya));
        da = (j0 == i) ? FINF : da;
        float dxb = pa.z - pi.x, dyb = pa.w - pi.y;
        float db = __fadd_rn(__fmul_rn(dxb, dxb), __fmul_rn(dyb, dyb));
        db = (j0 + 1 == i) ? FINF : db;
        mm0 = fminf(mm0, da); mm1 = fminf(mm1, db);
    }
    if ((n & 1) && half == 0 && lane == 0) {  // odd final point: one thread total
        float2 pj = sP[n - 1];
        float dx = pj.x - pi.x, dy = pj.y - pi.y;
        float d2 = __fadd_rn(__fmul_rn(dx, dx), __fmul_rn(dy, dy));
        d2 = (n - 1 == i) ? FINF : d2;
        mm2 = fminf(mm2, d2);
    }
    const float mn = fminf(fminf(mm0, mm1), fminf(mm2, mm3));

    // wave butterfly: top-4 of this wave's 64 lane-mins (sorted, wave-uniform)
    float A0 = mn, A1 = FINF, A2 = FINF, A3 = FINF;
    #pragma unroll
    for (int m = 1; m < 64; m <<= 1) {
        float y0 = __shfl_xor(A0, m), y1 = __shfl_xor(A1, m);
        float y2 = __shfl_xor(A2, m), y3 = __shfl_xor(A3, m);
        MRG4(A0, A1, A2, A3, y0, y1, y2, y3);
    }
    if (lane == 0) {
        float* d = &sTh[(g * 2 + half) * 4];
        d[0] = A0; d[1] = A1; d[2] = A2; d[3] = A3;
    }
    __syncthreads();
    {
        const float* po = &sTh[(g * 2 + (half ^ 1)) * 4];
        float y0 = po[0], y1 = po[1], y2 = po[2], y3 = po[3];
        MRG4(A0, A1, A2, A3, y0, y1, y2, y3);
    }
    const float thr = A3;   // 4th-smallest of 128 lane-mins >= exact 4th overall

    // ---------- phase 2: filtered INSU over this wave's half ----------
    u64 k0 = ~0ull, k1 = ~0ull, k2 = ~0ull, k3 = ~0ull;

    f = lane + (half << 6);
    for (; f < n2; f += 128) {
        float4 pa = s4[f];
        const int j0 = 2 * f;
        float dxa = pa.x - pi.x, dya = pa.y - pi.y;
        float da = __fadd_rn(__fmul_rn(dxa, dxa), __fmul_rn(dya, dya));
        if (da <= thr) {
            u64 key = (((u64)__float_as_uint(da)) << 24) | (unsigned)j0;
            key = (j0 == i) ? ~0ull : key;
            INSU(key);
        }
        float dxb = pa.z - pi.x, dyb = pa.w - pi.y;
        float db = __fadd_rn(__fmul_rn(dxb, dxb), __fmul_rn(dyb, dyb));
        if (db <= thr) {
            u64 key = (((u64)__float_as_uint(db)) << 24) | (unsigned)(j0 + 1);
            key = (j0 + 1 == i) ? ~0ull : key;
            INSU(key);
        }
    }
    if ((n & 1) && half == 0 && lane == 0) {
        float2 pj = sP[n - 1];
        float dx = pj.x - pi.x, dy = pj.y - pi.y;
        float d2 = __fadd_rn(__fmul_rn(dx, dx), __fmul_rn(dy, dy));
        if (d2 <= thr) {
            u64 key = (((u64)__float_as_uint(d2)) << 24) | (unsigned)(n - 1);
            key = (n - 1 == i) ? ~0ull : key;
            INSU(key);
        }
    }

    // wave u64 butterfly (r0/r9/r10-proven) -> wave-uniform top-4 of its half
    #pragma unroll
    for (int m = 1; m < 64; m <<= 1) {
        u64 o0 = __shfl_xor(k0, m), o1 = __shfl_xor(k1, m);
        u64 o2_ = __shfl_xor(k2, m), o3 = __shfl_xor(k3, m);
        INSU(o0); INSU(o1); INSU(o2_); INSU(o3);
    }
    if (lane == 0) {
        u64* d = &sKy[(g * 2 + half) * 4];
        d[0] = k0; d[1] = k1; d[2] = k2; d[3] = k3;
    }
    __syncthreads();

    if (half == 0) {
        const u64* pk = &sKy[(g * 2 + 1) * 4];
        u64 p0 = pk[0], p1 = pk[1], p2 = pk[2], p3 = pk[3];
        INSU(p0); INSU(p1); INSU(p2); INSU(p3);

        if (iraw < n && lane < 4) {
            u64 kq = (lane == 0) ? k0 : (lane == 1) ? k1 : (lane == 2) ? k2 : k3;
            int jn = (int)(kq & 0xFFFFFF);
            if (jn < 0 || jn >= n) jn = 0;
            float pix = pi.x, piy = pi.y;
            float pjx = obs2[2 * jn], pjy = obs2[2 * jn + 1];
            float px = pjx - pix, py = pjy - piy;
            float vix = pix - obs1[2 * i];
            float viy = piy - obs1[2 * i + 1];
            float vx = (pjx - obs1[2 * jn])     - vix;
            float vy = (pjy - obs1[2 * jn + 1]) - viy;
            float* dst = out + (size_t)i * 32 + lane * 8;
            #pragma unroll
            for (int e = 0; e < 8; e++) {
                float a = px * Wemb[e]      + py * Wemb[8 + e]
                        + vx * Wemb[16 + e] + vy * Wemb[24 + e]
                        + bemb[e];
                dst[e] = fmaxf(a, 0.0f);
            }
        }
    }
}

// K1 generic (r9 code, hardware-passed) — used when n doesn't fit LDS staging.
__global__ __launch_bounds__(256, 4) void knn_prep_kernel(
    const float* __restrict__ obs1, const float* __restrict__ obs2,
    const float* __restrict__ Wemb, const float* __restrict__ bemb,
    const float* __restrict__ Wih,  const float* __restrict__ Whh,
    const float* __restrict__ Wp,
    u16* __restrict__ Wgf, u16* __restrict__ Wpf,
    int n, int knn_blocks, float* __restrict__ out)
{
    const int t = threadIdx.x;

    if (blockIdx.x >= knn_blocks) {
        int id = (blockIdx.x - knn_blocks) * 256 + t;
        prep_item(id, Wih, Whh, Wp, Wgf, Wpf);
        return;
    }

    const int lane = t & 63;
    const int wv   = t >> 6;
    const int i    = blockIdx.x * 4 + wv;
    if (i >= n) return;

    const float FINF = __int_as_float(0x7f800000);
    const float2* o2 = (const float2*)obs2;
    const float4* o4 = (const float4*)obs2;
    const int n2 = n >> 1;
    const float2 pi = o2[i];

    float mm[8];
    #pragma unroll
    for (int q = 0; q < 8; q++) mm[q] = FINF;

    int f = lane;
    for (; f + 448 < n2; f += 512) {
        float4 p[8];
        #pragma unroll
        for (int q = 0; q < 8; q++) p[q] = o4[f + q * 64];
        #pragma unroll
        for (int q = 0; q < 8; q++) {
            const int j0 = 2 * (f + q * 64);
            float dxa = p[q].x - pi.x, dya = p[q].y - pi.y;
            float da = __fadd_rn(__fmul_rn(dxa, dxa), __fmul_rn(dya, dya));
            da = (j0 == i) ? FINF : da;
            float dxb = p[q].z - pi.x, dyb = p[q].w - pi.y;
            float db = __fadd_rn(__fmul_rn(dxb, dxb), __fmul_rn(dyb, dyb));
            db = (j0 + 1 == i) ? FINF : db;
            mm[q] = fminf(mm[q], fminf(da, db));
        }
    }
    for (; f < n2; f += 64) {
        float4 p = o4[f];
        const int j0 = 2 * f;
        float dxa = p.x - pi.x, dya = p.y - pi.y;
        float da = __fadd_rn(__fmul_rn(dxa, dxa), __fmul_rn(dya, dya));
        da = (j0 == i) ? FINF : da;
        float dxb = p.z - pi.x, dyb = p.w - pi.y;
        float db = __fadd_rn(__fmul_rn(dxb, dxb), __fmul_rn(dyb, dyb));
        db = (j0 + 1 == i) ? FINF : db;
        mm[0] = fminf(mm[0], fminf(da, db));
    }
    if ((n & 1) && lane == 0) {
        float2 pj = o2[n - 1];
        float dx = pj.x - pi.x, dy = pj.y - pi.y;
        float d2 = __fadd_rn(__fmul_rn(dx, dx), __fmul_rn(dy, dy));
        d2 = (n - 1 == i) ? FINF : d2;
        mm[1] = fminf(mm[1], d2);
    }
    const float mn = fminf(fminf(fminf(mm[0], mm[1]), fminf(mm[2], mm[3])),
                           fminf(fminf(mm[4], mm[5]), fminf(mm[6], mm[7])));

    float A0 = mn, A1 = FINF, A2 = FINF, A3 = FINF;
    #pragma unroll
    for (int m = 1; m < 64; m <<= 1) {
        float y0 = __shfl_xor(A0, m), y1 = __shfl_xor(A1, m);
        float y2 = __shfl_xor(A2, m), y3 = __shfl_xor(A3, m);
        MRG4(A0, A1, A2, A3, y0, y1, y2, y3);
    }
    const float thr = A3;

    u64 k0 = ~0ull, k1 = ~0ull, k2 = ~0ull, k3 = ~0ull;

    f = lane;
    for (; f < n2; f += 64) {
        float4 p = o4[f];
        const int j0 = 2 * f;
        float dxa = p.x - pi.x, dya = p.y - pi.y;
        float da = __fadd_rn(__fmul_rn(dxa, dxa), __fmul_rn(dya, dya));
        if (da <= thr) {
            u64 key = (((u64)__float_as_uint(da)) << 24) | (unsigned)j0;
            key = (j0 == i) ? ~0ull : key;
            INSU(key);
        }
        float dxb = p.z - pi.x, dyb = p.w - pi.y;
        float db = __fadd_rn(__fmul_rn(dxb, dxb), __fmul_rn(dyb, dyb));
        if (db <= thr) {
            u64 key = (((u64)__float_as_uint(db)) << 24) | (unsigned)(j0 + 1);
            key = (j0 + 1 == i) ? ~0ull : key;
            INSU(key);
        }
    }
    if ((n & 1) && lane == 0) {
        float2 pj = o2[n - 1];
        float dx = pj.x - pi.x, dy = pj.y - pi.y;
        float d2 = __fadd_rn(__fmul_rn(dx, dx), __fmul_rn(dy, dy));
        if (d2 <= thr) {
            u64 key = (((u64)__float_as_uint(d2)) << 24) | (unsigned)(n - 1);
            key = (n - 1 == i) ? ~0ull : key;
            INSU(key);
        }
    }

    #pragma unroll
    for (int m = 1; m < 64; m <<= 1) {
        u64 o0 = __shfl_xor(k0, m), o1 = __shfl_xor(k1, m);
        u64 o2_ = __shfl_xor(k2, m), o3 = __shfl_xor(k3, m);
        INSU(o0); INSU(o1); INSU(o2_); INSU(o3);
    }

    if (lane < 4) {
        u64 kq = (lane == 0) ? k0 : (lane == 1) ? k1 : (lane == 2) ? k2 : k3;
        int jn = (int)(kq & 0xFFFFFF);
        if (jn < 0 || jn >= n) jn = 0;
        float pix = pi.x, piy = pi.y;
        float pjx = obs2[2 * jn], pjy = obs2[2 * jn + 1];
        float px = pjx - pix, py = pjy - piy;
        float vix = pix - obs1[2 * i];
        float viy = piy - obs1[2 * i + 1];
        float vx = (pjx - obs1[2 * jn])     - vix;
        float vy = (pjy - obs1[2 * jn + 1]) - viy;
        float* dst = out + (size_t)i * 32 + lane * 8;
        #pragma unroll
        for (int e = 0; e < 8; e++) {
            float a = px * Wemb[e]      + py * Wemb[8 + e]
                    + vx * Wemb[16 + e] + vy * Wemb[24 + e]
                    + bemb[e];
            dst[e] = fmaxf(a, 0.0f);
        }
    }
}

// K2 (r12, HW-passed): 24-row blocks — grid = ceil(n/24) = 256 at n=6144.
// Each wave holds TWO A-row-fragments and reuses every B-fragment for 2 MFMAs.
__global__ __launch_bounds__(512) void lstm_kernel(
    const float* __restrict__ h,   const float* __restrict__ c,
    const u16*  __restrict__ Wgf,  const float* __restrict__ bih,
    const float* __restrict__ bhh,
    const u16*  __restrict__ Wpf,  const float* __restrict__ bp,
    int n, float* __restrict__ out)
{
    __shared__ __align__(16) char lds[35840];
    u16* sXb = (u16*)lds;                     // [32][296] bf16 X=[emb|h], rows 24-31 zero
    u16* sHb = (u16*)(lds + 18944);           // [32][264] bf16 h_new, rows 24-31 zero

    const int t    = threadIdx.x;             // 0..511
    const int i0   = blockIdx.x * 24;         // 24 rows per block
    const int lane = t & 63;
    const int wv   = t >> 6;                  // wave 0..7
    const int fm   = lane & 15;
    const int fq   = lane >> 4;

    // stage emb (fp32 in out) -> sXb[:,0:32): 32x32 entries, 2 per thread
    #pragma unroll
    for (int v = t; v < 32 * 32; v += 512) {
        int r = v >> 5, e = v & 31;           // r 0..31
        int row = i0 + r;
        float val = (r < 24 && row < n) ? out[(size_t)row * 32 + e] : 0.0f;
        sXb[r * 296 + e] = f2bf(val);
    }
    // stage h -> sXb[:,32:288): 32 rows x 64 float4, 4 per thread
    #pragma unroll
    for (int f = t; f < 32 * 64; f += 512) {
        int r = f >> 6, k4 = f & 63;
        int row = i0 + r;
        float4 hv = (r < 24 && row < n) ? ((const float4*)h)[(size_t)row * 64 + k4]
                                        : make_float4(0.f, 0.f, 0.f, 0.f);
        u16* d = &sXb[r * 296 + 32 + k4 * 4];
        d[0] = f2bf(hv.x); d[1] = f2bf(hv.y); d[2] = f2bf(hv.z); d[3] = f2bf(hv.w);
    }
    __syncthreads();

    // A-frags for TWO row-tiles: rows fm (tile0: rows 0..15) and fm+16 (tile1: 16..31)
    bf16x8 afr0[9], afr1[9];
    #pragma unroll
    for (int kt = 0; kt < 9; kt++) {
        afr0[kt] = *(const bf16x8*)&sXb[fm * 296 + kt * 32 + fq * 8];
        afr1[kt] = *(const bf16x8*)&sXb[(fm + 16) * 296 + kt * 32 + fq * 8];
    }

    // gates + pointwise, unit tiles {wv, wv+8}; each B-frag feeds 2 MFMAs
    #pragma unroll
    for (int ut2 = 0; ut2 < 2; ut2++) {
        const int ut = wv + ut2 * 8;          // unit tile 0..15
        const int u  = ut * 16 + fm;          // hidden unit this lane owns

        f32x4 acc0[4], acc1[4];
        #pragma unroll
        for (int jg = 0; jg < 4; jg++) { acc0[jg] = (f32x4){0.f,0.f,0.f,0.f};
                                         acc1[jg] = (f32x4){0.f,0.f,0.f,0.f}; }

        #pragma unroll
        for (int jg = 0; jg < 4; jg++) {      // gate type i,f,g,o
            const int gt = jg * 16 + ut;
            const u16* wbase = Wgf + ((size_t)gt * 9) * 512 + lane * 8;
            #pragma unroll
            for (int kt = 0; kt < 9; kt++) {
                bf16x8 bfr = *(const bf16x8*)(wbase + kt * 512);  // coalesced 1 KB
                acc0[jg] = __builtin_amdgcn_mfma_f32_16x16x32_bf16(afr0[kt], bfr, acc0[jg], 0, 0, 0);
                acc1[jg] = __builtin_amdgcn_mfma_f32_16x16x32_bf16(afr1[kt], bfr, acc1[jg], 0, 0, 0);
            }
        }

        float b0 = bih[u]       + bhh[u];
        float b1 = bih[u + 256] + bhh[u + 256];
        float b2 = bih[u + 512] + bhh[u + 512];
        float b3 = bih[u + 768] + bhh[u + 768];

        // tile0: local rows rl = fq*4 + r_ (0..15), all < 24
        #pragma unroll
        for (int r_ = 0; r_ < 4; r_++) {
            int rl = fq * 4 + r_;
            int row = i0 + rl;
            bool valid = (row < n);
            float cin = valid ? c[(size_t)row * 256 + u] : 0.0f;
            float gi = acc0[0][r_] + b0;
            float gf = acc0[1][r_] + b1;
            float gg = acc0[2][r_] + b2;
            float go = acc0[3][r_] + b3;
            float cn = sigf(gf) * cin + sigf(gi) * tanhf_(gg);
            float hn = sigf(go) * tanhf_(cn);
            sHb[rl * 264 + u] = valid ? f2bf(hn) : (u16)0;
        }
        // tile1: local rows rl = 16 + fq*4 + r_ (16..31), valid only rl < 24
        #pragma unroll
        for (int r_ = 0; r_ < 4; r_++) {
            int rl = 16 + fq * 4 + r_;
            int row = i0 + rl;
            bool valid = (rl < 24) && (row < n);
            float cin = valid ? c[(size_t)row * 256 + u] : 0.0f;
            float gi = acc1[0][r_] + b0;
            float gf = acc1[1][r_] + b1;
            float gg = acc1[2][r_] + b2;
            float go = acc1[3][r_] + b3;
            float cn = sigf(gf) * cin + sigf(gi) * tanhf_(gg);
            float hn = sigf(go) * tanhf_(cn);
            sHb[rl * 264 + u] = valid ? f2bf(hn) : (u16)0;
        }
    }
    __syncthreads();

    // pool GEMM: M=32 x N=32 x K=256; waves 0..3: row-tile = wv>>1, col-tile = wv&1
    if (wv < 4) {
        const int rt = wv >> 1;               // row tile 0/1
        const int nc = wv & 1;                // col tile 0/1
        bf16x8 ah[8];
        #pragma unroll
        for (int kt = 0; kt < 8; kt++)
            ah[kt] = *(const bf16x8*)&sHb[(fm + rt * 16) * 264 + kt * 32 + fq * 8];
        const u16* wbase = Wpf + ((size_t)nc * 8) * 512 + lane * 8;
        f32x4 acc = {0.f, 0.f, 0.f, 0.f};
        #pragma unroll
        for (int kt = 0; kt < 8; kt++) {
            bf16x8 bfr = *(const bf16x8*)(wbase + kt * 512);
            acc = __builtin_amdgcn_mfma_f32_16x16x32_bf16(ah[kt], bfr, acc, 0, 0, 0);
        }
        float bias = bp[nc * 16 + fm];
        #pragma unroll
        for (int r_ = 0; r_ < 4; r_++) {
            int rl = rt * 16 + fq * 4 + r_;
            int row = i0 + rl;
            if (rl < 24 && row < n) out[(size_t)row * 32 + nc * 16 + fm] = acc[r_] + bias;
        }
    }
}

// ---- round-5 fallback (no workspace) ----
__global__ __launch_bounds__(256) void nnlstm_fallback(
    const float* __restrict__ obs1, const float* __restrict__ obs2,
    const float* __restrict__ h,    const float* __restrict__ c,
    const float* __restrict__ Wemb, const float* __restrict__ bemb,
    const float* __restrict__ Wih,  const float* __restrict__ bih,
    const float* __restrict__ Whh,  const float* __restrict__ bhh,
    const float* __restrict__ Wp,   const float* __restrict__ bp,
    int n, float* __restrict__ out)
{
    __shared__ float sMd[16][64];
    __shared__ int   sMj[16][64];
    __shared__ float sX[16][292];
    __shared__ float sH[16][264];

    const int t   = threadIdx.x;
    const int sub = t & 15;
    const int ii  = t >> 4;
    const int i0  = blockIdx.x * 16;
    const int i   = i0 + ii;

    for (int v = t; v < 16 * 256; v += 256) {
        int r = v >> 8, k = v & 255;
        int row = i0 + r;
        sX[r][32 + k] = (row < n) ? h[(size_t)row * 256 + k] : 0.0f;
    }

    float bd0 = 1e30f, bd1 = 1e30f, bd2 = 1e30f, bd3 = 1e30f;
    int   bj0 = 0x7fffffff, bj1 = 0x7fffffff, bj2 = 0x7fffffff, bj3 = 0x7fffffff;

    if (i < n) {
        const float pix = obs2[2 * i];
        const float piy = obs2[2 * i + 1];
        for (int j = sub; j < n; j += 16) {
            float dx = obs2[2 * j]     - pix;
            float dy = obs2[2 * j + 1] - piy;
            float d2 = __fadd_rn(__fmul_rn(dx, dx), __fmul_rn(dy, dy));
            float dist = __fsqrt_rn(d2);
            if (j == i) continue;
            INS4(dist, j);
        }
    }
    sMd[ii][sub * 4 + 0] = bd0;  sMj[ii][sub * 4 + 0] = bj0;
    sMd[ii][sub * 4 + 1] = bd1;  sMj[ii][sub * 4 + 1] = bj1;
    sMd[ii][sub * 4 + 2] = bd2;  sMj[ii][sub * 4 + 2] = bj2;
    sMd[ii][sub * 4 + 3] = bd3;  sMj[ii][sub * 4 + 3] = bj3;
    __syncthreads();

    if (t < 16) {
        const int r = t;
        const int irow = i0 + r;
        float bd0 = 1e30f, bd1 = 1e30f, bd2 = 1e30f, bd3 = 1e30f;
        int   bj0 = 0x7fffffff, bj1 = 0x7fffffff, bj2 = 0x7fffffff, bj3 = 0x7fffffff;
        for (int q = 0; q < 64; q++) { INS4(sMd[r][q], sMj[r][q]); }

        if (irow < n) {
            float pix = obs2[2 * irow], piy = obs2[2 * irow + 1];
            float vix = pix - obs1[2 * irow];
            float viy = piy - obs1[2 * irow + 1];
            #pragma unroll
            for (int q2 = 0; q2 < 4; q2++) {
                int jn = (q2 == 0) ? bj0 : (q2 == 1) ? bj1 : (q2 == 2) ? bj2 : bj3;
                if (jn < 0 || jn >= n) jn = 0;
                float pjx = obs2[2 * jn], pjy = obs2[2 * jn + 1];
                float px = pjx - pix, py = pjy - piy;
                float vx = (pjx - obs1[2 * jn])     - vix;
                float vy = (pjy - obs1[2 * jn + 1]) - viy;
                #pragma unroll
                for (int e = 0; e < 8; e++) {
                    float a = px * Wemb[e]      + py * Wemb[8 + e]
                            + vx * Wemb[16 + e] + vy * Wemb[24 + e]
                            + bemb[e];
                    sX[r][q2 * 8 + e] = fmaxf(a, 0.0f);
                }
            }
        } else {
            for (int e = 0; e < 32; e++) sX[r][e] = 0.0f;
        }
    }
    __syncthreads();

    const int uu = t;
    float acc[4][16];
    #pragma unroll
    for (int j = 0; j < 4; j++) {
        float b = bih[uu + 256 * j] + bhh[uu + 256 * j];
        #pragma unroll
        for (int r = 0; r < 16; r++) acc[j][r] = b;
    }

    for (int kc = 0; kc < 288; kc++) {
        float w[4];
        #pragma unroll
        for (int j = 0; j < 4; j++) {
            int g = uu + 256 * j;
            w[j] = (kc < 32) ? Wih[(size_t)g * 32 + kc]
                             : Whh[(size_t)g * 256 + (kc - 32)];
        }
        #pragma unroll
        for (int r = 0; r < 16; r++) {
            float x = sX[r][kc];
            #pragma unroll
            for (int j = 0; j < 4; j++) acc[j][r] += w[j] * x;
        }
    }

    for (int r = 0; r < 16; r++) {
        int row = i0 + r;
        float cin = (row < n) ? c[(size_t)row * 256 + uu] : 0.0f;
        float cn = sigf(acc[1][r]) * cin + sigf(acc[0][r]) * tanhf(acc[2][r]);
        float hn = sigf(acc[3][r]) * tanhf(cn);
        sH[r][uu] = hn;
    }
    __syncthreads();

    for (int v = t; v < 16 * 32; v += 256) {
        int r = v >> 5, o = v & 31;
        int row = i0 + r;
        if (row >= n) continue;
        float a = bp[o];
        for (int kc = 0; kc < 256; kc++)
            a += Wp[(size_t)o * 256 + kc] * sH[r][kc];
        out[(size_t)row * 32 + o] = a;
    }
}

extern "C" void kernel_launch(void* const* d_in, const int* in_sizes, int n_in,
                              void* d_out, int out_size, void* d_ws, size_t ws_size,
                              hipStream_t stream) {
    float* out = (float*)d_out;

    int code = 0, n = 0;
    if (n_in != 12) code = 1;
    else {
        n = in_sizes[1] / 2;
        if (n <= 4 || in_sizes[1] != 2 * n)          code = 2;
        else if (in_sizes[0]  != 2 * n)              code = 3;
        else if (in_sizes[2]  != 256 * n)            code = 4;
        else if (in_sizes[3]  != 256 * n)            code = 5;
        else if (in_sizes[4]  != 32 || in_sizes[5] != 8)        code = 6;
        else if (in_sizes[6]  != 32768 || in_sizes[7] != 1024)  code = 7;
        else if (in_sizes[8]  != 262144 || in_sizes[9] != 1024) code = 8;
        else if (in_sizes[10] != 8192 || in_sizes[11] != 32)    code = 9;
        else if (out_size != 32 * n)                 code = 10;
    }
    if (code != 0) {
        diag_kernel<<<1, 1, 0, stream>>>(out, code, out_size);
        return;
    }

    const float* obs1   = (const float*)d_in[0];
    const float* obs2   = (const float*)d_in[1];
    const float* h      = (const float*)d_in[2];
    const float* c      = (const float*)d_in[3];
    const float* W_emb  = (const float*)d_in[4];
    const float* b_emb  = (const float*)d_in[5];
    const float* W_ih   = (const float*)d_in[6];
    const float* b_ih   = (const float*)d_in[7];
    const float* W_hh   = (const float*)d_in[8];
    const float* b_hh   = (const float*)d_in[9];
    const float* W_pool = (const float*)d_in[10];
    const float* b_pool = (const float*)d_in[11];

    const size_t wgf_bytes = (size_t)36864 * 8 * sizeof(u16);   // 589,824
    const size_t wpf_bytes = (size_t)1024 * 8 * sizeof(u16);    //  16,384

    if (ws_size >= wgf_bytes + wpf_bytes && n <= (1 << 24)) {
        u16* Wgf = (u16*)d_ws;
        u16* Wpf = (u16*)((char*)d_ws + wgf_bytes);
        const size_t stage_bytes = (size_t)((n + 1) & ~1) * 8;  // pair-rounded
        if (stage_bytes + 1024 <= 65536 && stage_bytes <= 49152) {  // n <= 6144: LDS path
            int knn_blocks = (n + 7) / 8;                       // 8 peds/block (16 waves)
            int prep_blocks = (37888 + 1023) / 1024;            // 37
            knn_prep_lds_kernel<<<knn_blocks + prep_blocks, 1024,
                                  stage_bytes + 1024, stream>>>(
                obs1, obs2, W_emb, b_emb, W_ih, W_hh, W_pool, Wgf, Wpf,
                n, knn_blocks, out);
        } else {
            int knn_blocks = (n + 3) / 4;
            knn_prep_kernel<<<knn_blocks + 148, 256, 0, stream>>>(
                obs1, obs2, W_emb, b_emb, W_ih, W_hh, W_pool, Wgf, Wpf,
                n, knn_blocks, out);
        }
        lstm_kernel<<<(n + 23) / 24, 512, 0, stream>>>(
            h, c, Wgf, b_ih, b_hh, Wpf, b_pool, n, out);
    } else {
        nnlstm_fallback<<<(n + 15) / 16, 256, 0, stream>>>(
            obs1, obs2, h, c, W_emb, b_emb, W_ih, b_ih, W_hh, b_hh,
            W_pool, b_pool, n, out);
    }
}

// Round 14
// 129.804 us; speedup vs baseline: 1.0608x; 1.0608x over previous
//
#include <hip/hip_runtime.h>
#include <math.h>

typedef unsigned short u16;
typedef unsigned long long u64;
typedef __attribute__((ext_vector_type(8))) short bf16x8;
typedef __attribute__((ext_vector_type(4))) float f32x4;

__device__ __forceinline__ float sigf(float x)  { return 1.0f / (1.0f + __expf(-x)); }
__device__ __forceinline__ float tanhf_(float x){ float e = __expf(2.0f * x); return 1.0f - 2.0f / (e + 1.0f); }
__device__ __forceinline__ u16 f2bf(float f) {
    unsigned x = __float_as_uint(f);
    return (u16)((x + 0x7fffu + ((x >> 16) & 1u)) >> 16);
}

// u64-key sorted insert: keys k0<=k1<=k2<=k3, key = (asuint(d2)<<24)|idx.
// (d2,idx) order == np's (dist,idx) order — verified bit-identical r14/r0/r1/r4/r5/r6/r9/r10/r12.
#define INSU(KEY) do {                                                              \
    u64 _k = (KEY);                                                                 \
    k3 = (_k < k3) ? _k : k3;                                                       \
    { bool _c = k3 < k2; u64 _lo = _c ? k3 : k2, _hi = _c ? k2 : k3; k2 = _lo; k3 = _hi; } \
    { bool _c = k2 < k1; u64 _lo = _c ? k2 : k1, _hi = _c ? k1 : k2; k1 = _lo; k2 = _hi; } \
    { bool _c = k1 < k0; u64 _lo = _c ? k1 : k0, _hi = _c ? k0 : k1; k0 = _lo; k1 = _hi; } \
} while (0)

// merge two ascending sorted-4 float lists, keep lowest 4 sorted in X (bitonic).
// (hardware-proven r1/r4/r5/r6/r9/r10/r12)
#define MRG4(X0,X1,X2,X3,Y0,Y1,Y2,Y3) do {                                          \
    float _q0 = fminf((X0),(Y3));                                                   \
    float _q1 = fminf((X1),(Y2));                                                   \
    float _q2 = fminf((X2),(Y1));                                                   \
    float _q3 = fminf((X3),(Y0));                                                   \
    float _l0 = fminf(_q0,_q2), _h0 = fmaxf(_q0,_q2);                               \
    float _l1 = fminf(_q1,_q3), _h1 = fmaxf(_q1,_q3);                               \
    (X0) = fminf(_l0,_l1); (X1) = fmaxf(_l0,_l1);                                   \
    (X2) = fminf(_h0,_h1); (X3) = fmaxf(_h0,_h1);                                   \
} while (0)

#define INS4(D, J) do {                                                              \
    float _d = (D); int _j = (J);                                                    \
    if (_d < bd3 || (_d == bd3 && _j < bj3)) {                                       \
        bd3 = _d; bj3 = _j;                                                          \
        if (bd3 < bd2 || (bd3 == bd2 && bj3 < bj2)) {                                \
            float _t = bd2; bd2 = bd3; bd3 = _t; int _u = bj2; bj2 = bj3; bj3 = _u; }\
        if (bd2 < bd1 || (bd2 == bd1 && bj2 < bj1)) {                                \
            float _t = bd1; bd1 = bd2; bd2 = _t; int _u = bj1; bj1 = bj2; bj2 = _u; }\
        if (bd1 < bd0 || (bd1 == bd0 && bj1 < bj0)) {                                \
            float _t = bd0; bd0 = bd1; bd1 = _t; int _u = bj0; bj0 = bj1; bj1 = _u; }\
    } } while (0)

__global__ void diag_kernel(float* out, int code, int out_size) {
    if (out_size > 0) out[0] = (float)code * 1.0e8f;
}

// prep: same (g,k)->Wgf/Wpf mapping as all passing rounds; loads as 2x float4
// (condition uniform per thread; values byte-identical). Passed r6/r9/r10/r12.
__device__ __forceinline__ void prep_item(
    int id, const float* Wih, const float* Whh, const float* Wp,
    u16* Wgf, u16* Wpf)
{
    if (id < 36864) {                        // gates: 64 gt * 9 kt * 64 lanes
        int gt = id / 576, rem = id - gt * 576;
        int kt = rem >> 6, ln = rem & 63;
        int g  = gt * 16 + (ln & 15);
        int k  = kt * 32 + (ln >> 4) * 8;
        u16* dst = Wgf + (size_t)id * 8;
        const float* src = (k < 32) ? (Wih + (size_t)g * 32 + k)
                                    : (Whh + (size_t)g * 256 + (k - 32));
        float4 v0 = ((const float4*)src)[0];
        float4 v1 = ((const float4*)src)[1];
        dst[0] = f2bf(v0.x); dst[1] = f2bf(v0.y); dst[2] = f2bf(v0.z); dst[3] = f2bf(v0.w);
        dst[4] = f2bf(v1.x); dst[5] = f2bf(v1.y); dst[6] = f2bf(v1.z); dst[7] = f2bf(v1.w);
    } else if (id < 37888) {                 // pool: 2 pt * 8 kt * 64 lanes
        int id2 = id - 36864;
        int pt = id2 >> 9, rem = id2 & 511;
        int kt = rem >> 6, ln = rem & 63;
        int o  = pt * 16 + (ln & 15);
        int k  = kt * 32 + (ln >> 4) * 8;
        u16* dst = Wpf + (size_t)id2 * 8;
        const float* src = Wp + (size_t)o * 256 + k;
        float4 v0 = ((const float4*)src)[0];
        float4 v1 = ((const float4*)src)[1];
        dst[0] = f2bf(v0.x); dst[1] = f2bf(v0.y); dst[2] = f2bf(v0.z); dst[3] = f2bf(v0.w);
        dst[4] = f2bf(v1.x); dst[5] = f2bf(v1.y); dst[6] = f2bf(v1.z); dst[7] = f2bf(v1.w);
    }
}

// K1-LDS (r14 = r12 = r10-exact, HW-passed at 130.88us total): two-phase scan
// from a block-shared 48KB LDS stage, 512 threads = 8 waves = 8 peds. This is
// the verified optimum of a 10-variant family: r11 single-pass (47us), r13
// two-waves-per-ped (44us), r4 global/LDS (flat), r5/r6 VALU cuts (flat) all
// lose to this structure's ~36us.
__global__ __launch_bounds__(512, 6) void knn_prep_lds_kernel(
    const float* __restrict__ obs1, const float* __restrict__ obs2,
    const float* __restrict__ Wemb, const float* __restrict__ bemb,
    const float* __restrict__ Wih,  const float* __restrict__ Whh,
    const float* __restrict__ Wp,
    u16* __restrict__ Wgf, u16* __restrict__ Wpf,
    int n, int knn_blocks, float* __restrict__ out)
{
    extern __shared__ __align__(16) char smem[];
    float4* s4 = (float4*)smem;               // [n/2] staged obs2 pairs
    float2* sP = (float2*)smem;               // float2 view (odd tail)

    const int t = threadIdx.x;                // 0..511

    if (blockIdx.x >= knn_blocks) {           // whole block -> prep (no barrier below runs)
        int id = (blockIdx.x - knn_blocks) * 512 + t;
        prep_item(id, Wih, Whh, Wp, Wgf, Wpf);
        return;
    }

    const float FINF = __int_as_float(0x7f800000);
    const float2* o2 = (const float2*)obs2;
    const float4* o4 = (const float4*)obs2;
    const int n2 = n >> 1;                    // point-pairs

    // ---- stage obs2 -> LDS, coalesced float4 (r4/r10-proven pattern) ----
    for (int idx = t; idx < n2; idx += 512) s4[idx] = o4[idx];
    if ((n & 1) && t == 0) sP[n - 1] = o2[n - 1];
    __syncthreads();                          // all threads reach (no prior return)

    const int lane = t & 63;
    const int wv   = t >> 6;                  // 0..7
    const int i    = blockIdx.x * 8 + wv;
    if (i >= n) return;                       // after barrier: no more barriers below

    const float2 pi = o2[i];

    // ---------- phase 1: lane-min scan from LDS (float4, 2 pts/read) ----------
    float mm0 = FINF, mm1 = FINF, mm2 = FINF, mm3 = FINF;

    int f = lane;
    for (; f + 64 < n2; f += 128) {           // 2 ds_read_b128 in flight
        float4 pa = s4[f], pb = s4[f + 64];
        int j0 = 2 * f;
        float dxa = pa.x - pi.x, dya = pa.y - pi.y;
        float da = __fadd_rn(__fmul_rn(dxa, dxa), __fmul_rn(dya, dya));
        da = (j0 == i) ? FINF : da;
        float dxb = pa.z - pi.x, dyb = pa.w - pi.y;
        float db = __fadd_rn(__fmul_rn(dxb, dxb), __fmul_rn(dyb, dyb));
        db = (j0 + 1 == i) ? FINF : db;
        mm0 = fminf(mm0, da); mm1 = fminf(mm1, db);
        int j1 = 2 * (f + 64);
        float dxc = pb.x - pi.x, dyc = pb.y - pi.y;
        float dc = __fadd_rn(__fmul_rn(dxc, dxc), __fmul_rn(dyc, dyc));
        dc = (j1 == i) ? FINF : dc;
        float dxd = pb.z - pi.x, dyd = pb.w - pi.y;
        float dd = __fadd_rn(__fmul_rn(dxd, dxd), __fmul_rn(dyd, dyd));
        dd = (j1 + 1 == i) ? FINF : dd;
        mm2 = fminf(mm2, dc); mm3 = fminf(mm3, dd);
    }
    for (; f < n2; f += 64) {
        float4 pa = s4[f];
        int j0 = 2 * f;
        float dxa = pa.x - pi.x, dya = pa.y - pi.y;
        float da = __fadd_rn(__fmul_rn(dxa, dxa), __fmul_rn(dya, dya));
        da = (j0 == i) ? FINF : da;
        float dxb = pa.z - pi.x, dyb = pa.w - pi.y;
        float db = __fadd_rn(__fmul_rn(dxb, dxb), __fmul_rn(dyb, dyb));
        db = (j0 + 1 == i) ? FINF : db;
        mm0 = fminf(mm0, da); mm1 = fminf(mm1, db);
    }
    if ((n & 1) && lane == 0) {               // odd final point: lane 0 only (disjoint)
        float2 pj = sP[n - 1];
        float dx = pj.x - pi.x, dy = pj.y - pi.y;
        float d2 = __fadd_rn(__fmul_rn(dx, dx), __fmul_rn(dy, dy));
        d2 = (n - 1 == i) ? FINF : d2;
        mm2 = fminf(mm2, d2);
    }
    const float mn = fminf(fminf(mm0, mm1), fminf(mm2, mm3));

    // butterfly top-4 of the 64 lane-mins (r5/r6/r9/r10-proven, seeded (mn,INF,INF,INF))
    float A0 = mn, A1 = FINF, A2 = FINF, A3 = FINF;
    #pragma unroll
    for (int m = 1; m < 64; m <<= 1) {
        float y0 = __shfl_xor(A0, m), y1 = __shfl_xor(A1, m);
        float y2 = __shfl_xor(A2, m), y3 = __shfl_xor(A3, m);
        MRG4(A0, A1, A2, A3, y0, y1, y2, y3);
    }
    const float thr = A3;   // >= exact 4th-smallest non-self d2 (subset order stat)

    // ---------- phase 2: exact (d2,idx) top-4 from LDS, filtered INSU ----------
    u64 k0 = ~0ull, k1 = ~0ull, k2 = ~0ull, k3 = ~0ull;

    f = lane;
    for (; f < n2; f += 64) {
        float4 pa = s4[f];
        const int j0 = 2 * f;
        float dxa = pa.x - pi.x, dya = pa.y - pi.y;
        float da = __fadd_rn(__fmul_rn(dxa, dxa), __fmul_rn(dya, dya));
        if (da <= thr) {
            u64 key = (((u64)__float_as_uint(da)) << 24) | (unsigned)j0;
            key = (j0 == i) ? ~0ull : key;
            INSU(key);
        }
        float dxb = pa.z - pi.x, dyb = pa.w - pi.y;
        float db = __fadd_rn(__fmul_rn(dxb, dxb), __fmul_rn(dyb, dyb));
        if (db <= thr) {
            u64 key = (((u64)__float_as_uint(db)) << 24) | (unsigned)(j0 + 1);
            key = (j0 + 1 == i) ? ~0ull : key;
            INSU(key);
        }
    }
    if ((n & 1) && lane == 0) {
        float2 pj = sP[n - 1];
        float dx = pj.x - pi.x, dy = pj.y - pi.y;
        float d2 = __fadd_rn(__fmul_rn(dx, dx), __fmul_rn(dy, dy));
        if (d2 <= thr) {
            u64 key = (((u64)__float_as_uint(d2)) << 24) | (unsigned)(n - 1);
            key = (n - 1 == i) ? ~0ull : key;
            INSU(key);
        }
    }

    #pragma unroll
    for (int m = 1; m < 64; m <<= 1) {
        u64 o0 = __shfl_xor(k0, m), o1 = __shfl_xor(k1, m);
        u64 o2_ = __shfl_xor(k2, m), o3 = __shfl_xor(k3, m);
        INSU(o0); INSU(o1); INSU(o2_); INSU(o3);
    }

    if (lane < 4) {
        u64 kq = (lane == 0) ? k0 : (lane == 1) ? k1 : (lane == 2) ? k2 : k3;
        int jn = (int)(kq & 0xFFFFFF);
        if (jn < 0 || jn >= n) jn = 0;
        float pix = pi.x, piy = pi.y;
        float pjx = obs2[2 * jn], pjy = obs2[2 * jn + 1];
        float px = pjx - pix, py = pjy - piy;
        float vix = pix - obs1[2 * i];
        float viy = piy - obs1[2 * i + 1];
        float vx = (pjx - obs1[2 * jn])     - vix;
        float vy = (pjy - obs1[2 * jn + 1]) - viy;
        float* dst = out + (size_t)i * 32 + lane * 8;
        #pragma unroll
        for (int e = 0; e < 8; e++) {
            float a = px * Wemb[e]      + py * Wemb[8 + e]
                    + vx * Wemb[16 + e] + vy * Wemb[24 + e]
                    + bemb[e];
            dst[e] = fmaxf(a, 0.0f);
        }
    }
}

// K1 generic (r9 code, hardware-passed) — used when n doesn't fit LDS staging.
__global__ __launch_bounds__(256, 4) void knn_prep_kernel(
    const float* __restrict__ obs1, const float* __restrict__ obs2,
    const float* __restrict__ Wemb, const float* __restrict__ bemb,
    const float* __restrict__ Wih,  const float* __restrict__ Whh,
    const float* __restrict__ Wp,
    u16* __restrict__ Wgf, u16* __restrict__ Wpf,
    int n, int knn_blocks, float* __restrict__ out)
{
    const int t = threadIdx.x;

    if (blockIdx.x >= knn_blocks) {
        int id = (blockIdx.x - knn_blocks) * 256 + t;
        prep_item(id, Wih, Whh, Wp, Wgf, Wpf);
        return;
    }

    const int lane = t & 63;
    const int wv   = t >> 6;
    const int i    = blockIdx.x * 4 + wv;
    if (i >= n) return;

    const float FINF = __int_as_float(0x7f800000);
    const float2* o2 = (const float2*)obs2;
    const float4* o4 = (const float4*)obs2;
    const int n2 = n >> 1;
    const float2 pi = o2[i];

    float mm[8];
    #pragma unroll
    for (int q = 0; q < 8; q++) mm[q] = FINF;

    int f = lane;
    for (; f + 448 < n2; f += 512) {
        float4 p[8];
        #pragma unroll
        for (int q = 0; q < 8; q++) p[q] = o4[f + q * 64];
        #pragma unroll
        for (int q = 0; q < 8; q++) {
            const int j0 = 2 * (f + q * 64);
            float dxa = p[q].x - pi.x, dya = p[q].y - pi.y;
            float da = __fadd_rn(__fmul_rn(dxa, dxa), __fmul_rn(dya, dya));
            da = (j0 == i) ? FINF : da;
            float dxb = p[q].z - pi.x, dyb = p[q].w - pi.y;
            float db = __fadd_rn(__fmul_rn(dxb, dxb), __fmul_rn(dyb, dyb));
            db = (j0 + 1 == i) ? FINF : db;
            mm[q] = fminf(mm[q], fminf(da, db));
        }
    }
    for (; f < n2; f += 64) {
        float4 p = o4[f];
        const int j0 = 2 * f;
        float dxa = p.x - pi.x, dya = p.y - pi.y;
        float da = __fadd_rn(__fmul_rn(dxa, dxa), __fmul_rn(dya, dya));
        da = (j0 == i) ? FINF : da;
        float dxb = p.z - pi.x, dyb = p.w - pi.y;
        float db = __fadd_rn(__fmul_rn(dxb, dxb), __fmul_rn(dyb, dyb));
        db = (j0 + 1 == i) ? FINF : db;
        mm[0] = fminf(mm[0], fminf(da, db));
    }
    if ((n & 1) && lane == 0) {
        float2 pj = o2[n - 1];
        float dx = pj.x - pi.x, dy = pj.y - pi.y;
        float d2 = __fadd_rn(__fmul_rn(dx, dx), __fmul_rn(dy, dy));
        d2 = (n - 1 == i) ? FINF : d2;
        mm[1] = fminf(mm[1], d2);
    }
    const float mn = fminf(fminf(fminf(mm[0], mm[1]), fminf(mm[2], mm[3])),
                           fminf(fminf(mm[4], mm[5]), fminf(mm[6], mm[7])));

    float A0 = mn, A1 = FINF, A2 = FINF, A3 = FINF;
    #pragma unroll
    for (int m = 1; m < 64; m <<= 1) {
        float y0 = __shfl_xor(A0, m), y1 = __shfl_xor(A1, m);
        float y2 = __shfl_xor(A2, m), y3 = __shfl_xor(A3, m);
        MRG4(A0, A1, A2, A3, y0, y1, y2, y3);
    }
    const float thr = A3;

    u64 k0 = ~0ull, k1 = ~0ull, k2 = ~0ull, k3 = ~0ull;

    f = lane;
    for (; f < n2; f += 64) {
        float4 p = o4[f];
        const int j0 = 2 * f;
        float dxa = p.x - pi.x, dya = p.y - pi.y;
        float da = __fadd_rn(__fmul_rn(dxa, dxa), __fmul_rn(dya, dya));
        if (da <= thr) {
            u64 key = (((u64)__float_as_uint(da)) << 24) | (unsigned)j0;
            key = (j0 == i) ? ~0ull : key;
            INSU(key);
        }
        float dxb = p.z - pi.x, dyb = p.w - pi.y;
        float db = __fadd_rn(__fmul_rn(dxb, dxb), __fmul_rn(dyb, dyb));
        if (db <= thr) {
            u64 key = (((u64)__float_as_uint(db)) << 24) | (unsigned)(j0 + 1);
            key = (j0 + 1 == i) ? ~0ull : key;
            INSU(key);
        }
    }
    if ((n & 1) && lane == 0) {
        float2 pj = o2[n - 1];
        float dx = pj.x - pi.x, dy = pj.y - pi.y;
        float d2 = __fadd_rn(__fmul_rn(dx, dx), __fmul_rn(dy, dy));
        if (d2 <= thr) {
            u64 key = (((u64)__float_as_uint(d2)) << 24) | (unsigned)(n - 1);
            key = (n - 1 == i) ? ~0ull : key;
            INSU(key);
        }
    }

    #pragma unroll
    for (int m = 1; m < 64; m <<= 1) {
        u64 o0 = __shfl_xor(k0, m), o1 = __shfl_xor(k1, m);
        u64 o2_ = __shfl_xor(k2, m), o3 = __shfl_xor(k3, m);
        INSU(o0); INSU(o1); INSU(o2_); INSU(o3);
    }

    if (lane < 4) {
        u64 kq = (lane == 0) ? k0 : (lane == 1) ? k1 : (lane == 2) ? k2 : k3;
        int jn = (int)(kq & 0xFFFFFF);
        if (jn < 0 || jn >= n) jn = 0;
        float pix = pi.x, piy = pi.y;
        float pjx = obs2[2 * jn], pjy = obs2[2 * jn + 1];
        float px = pjx - pix, py = pjy - piy;
        float vix = pix - obs1[2 * i];
        float viy = piy - obs1[2 * i + 1];
        float vx = (pjx - obs1[2 * jn])     - vix;
        float vy = (pjy - obs1[2 * jn + 1]) - viy;
        float* dst = out + (size_t)i * 32 + lane * 8;
        #pragma unroll
        for (int e = 0; e < 8; e++) {
            float a = px * Wemb[e]      + py * Wemb[8 + e]
                    + vx * Wemb[16 + e] + vy * Wemb[24 + e]
                    + bemb[e];
            dst[e] = fmaxf(a, 0.0f);
        }
    }
}

// K2 (r12, HW-passed): 24-row blocks — grid = ceil(n/24) = 256 at n=6144.
// Each wave holds TWO A-row-fragments and reuses every B-fragment for 2 MFMAs.
__global__ __launch_bounds__(512) void lstm_kernel(
    const float* __restrict__ h,   const float* __restrict__ c,
    const u16*  __restrict__ Wgf,  const float* __restrict__ bih,
    const float* __restrict__ bhh,
    const u16*  __restrict__ Wpf,  const float* __restrict__ bp,
    int n, float* __restrict__ out)
{
    __shared__ __align__(16) char lds[35840];
    u16* sXb = (u16*)lds;                     // [32][296] bf16 X=[emb|h], rows 24-31 zero
    u16* sHb = (u16*)(lds + 18944);           // [32][264] bf16 h_new, rows 24-31 zero

    const int t    = threadIdx.x;             // 0..511
    const int i0   = blockIdx.x * 24;         // 24 rows per block
    const int lane = t & 63;
    const int wv   = t >> 6;                  // wave 0..7
    const int fm   = lane & 15;
    const int fq   = lane >> 4;

    // stage emb (fp32 in out) -> sXb[:,0:32): 32x32 entries, 2 per thread
    #pragma unroll
    for (int v = t; v < 32 * 32; v += 512) {
        int r = v >> 5, e = v & 31;           // r 0..31
        int row = i0 + r;
        float val = (r < 24 && row < n) ? out[(size_t)row * 32 + e] : 0.0f;
        sXb[r * 296 + e] = f2bf(val);
    }
    // stage h -> sXb[:,32:288): 32 rows x 64 float4, 4 per thread
    #pragma unroll
    for (int f = t; f < 32 * 64; f += 512) {
        int r = f >> 6, k4 = f & 63;
        int row = i0 + r;
        float4 hv = (r < 24 && row < n) ? ((const float4*)h)[(size_t)row * 64 + k4]
                                        : make_float4(0.f, 0.f, 0.f, 0.f);
        u16* d = &sXb[r * 296 + 32 + k4 * 4];
        d[0] = f2bf(hv.x); d[1] = f2bf(hv.y); d[2] = f2bf(hv.z); d[3] = f2bf(hv.w);
    }
    __syncthreads();

    // A-frags for TWO row-tiles: rows fm (tile0: rows 0..15) and fm+16 (tile1: 16..31)
    bf16x8 afr0[9], afr1[9];
    #pragma unroll
    for (int kt = 0; kt < 9; kt++) {
        afr0[kt] = *(const bf16x8*)&sXb[fm * 296 + kt * 32 + fq * 8];
        afr1[kt] = *(const bf16x8*)&sXb[(fm + 16) * 296 + kt * 32 + fq * 8];
    }

    // gates + pointwise, unit tiles {wv, wv+8}; each B-frag feeds 2 MFMAs
    #pragma unroll
    for (int ut2 = 0; ut2 < 2; ut2++) {
        const int ut = wv + ut2 * 8;          // unit tile 0..15
        const int u  = ut * 16 + fm;          // hidden unit this lane owns

        f32x4 acc0[4], acc1[4];
        #pragma unroll
        for (int jg = 0; jg < 4; jg++) { acc0[jg] = (f32x4){0.f,0.f,0.f,0.f};
                                         acc1[jg] = (f32x4){0.f,0.f,0.f,0.f}; }

        #pragma unroll
        for (int jg = 0; jg < 4; jg++) {      // gate type i,f,g,o
            const int gt = jg * 16 + ut;
            const u16* wbase = Wgf + ((size_t)gt * 9) * 512 + lane * 8;
            #pragma unroll
            for (int kt = 0; kt < 9; kt++) {
                bf16x8 bfr = *(const bf16x8*)(wbase + kt * 512);  // coalesced 1 KB
                acc0[jg] = __builtin_amdgcn_mfma_f32_16x16x32_bf16(afr0[kt], bfr, acc0[jg], 0, 0, 0);
                acc1[jg] = __builtin_amdgcn_mfma_f32_16x16x32_bf16(afr1[kt], bfr, acc1[jg], 0, 0, 0);
            }
        }

        float b0 = bih[u]       + bhh[u];
        float b1 = bih[u + 256] + bhh[u + 256];
        float b2 = bih[u + 512] + bhh[u + 512];
        float b3 = bih[u + 768] + bhh[u + 768];

        // tile0: local rows rl = fq*4 + r_ (0..15), all < 24
        #pragma unroll
        for (int r_ = 0; r_ < 4; r_++) {
            int rl = fq * 4 + r_;
            int row = i0 + rl;
            bool valid = (row < n);
            float cin = valid ? c[(size_t)row * 256 + u] : 0.0f;
            float gi = acc0[0][r_] + b0;
            float gf = acc0[1][r_] + b1;
            float gg = acc0[2][r_] + b2;
            float go = acc0[3][r_] + b3;
            float cn = sigf(gf) * cin + sigf(gi) * tanhf_(gg);
            float hn = sigf(go) * tanhf_(cn);
            sHb[rl * 264 + u] = valid ? f2bf(hn) : (u16)0;
        }
        // tile1: local rows rl = 16 + fq*4 + r_ (16..31), valid only rl < 24
        #pragma unroll
        for (int r_ = 0; r_ < 4; r_++) {
            int rl = 16 + fq * 4 + r_;
            int row = i0 + rl;
            bool valid = (rl < 24) && (row < n);
            float cin = valid ? c[(size_t)row * 256 + u] : 0.0f;
            float gi = acc1[0][r_] + b0;
            float gf = acc1[1][r_] + b1;
            float gg = acc1[2][r_] + b2;
            float go = acc1[3][r_] + b3;
            float cn = sigf(gf) * cin + sigf(gi) * tanhf_(gg);
            float hn = sigf(go) * tanhf_(cn);
            sHb[rl * 264 + u] = valid ? f2bf(hn) : (u16)0;
        }
    }
    __syncthreads();

    // pool GEMM: M=32 x N=32 x K=256; waves 0..3: row-tile = wv>>1, col-tile = wv&1
    if (wv < 4) {
        const int rt = wv >> 1;               // row tile 0/1
        const int nc = wv & 1;                // col tile 0/1
        bf16x8 ah[8];
        #pragma unroll
        for (int kt = 0; kt < 8; kt++)
            ah[kt] = *(const bf16x8*)&sHb[(fm + rt * 16) * 264 + kt * 32 + fq * 8];
        const u16* wbase = Wpf + ((size_t)nc * 8) * 512 + lane * 8;
        f32x4 acc = {0.f, 0.f, 0.f, 0.f};
        #pragma unroll
        for (int kt = 0; kt < 8; kt++) {
            bf16x8 bfr = *(const bf16x8*)(wbase + kt * 512);
            acc = __builtin_amdgcn_mfma_f32_16x16x32_bf16(ah[kt], bfr, acc, 0, 0, 0);
        }
        float bias = bp[nc * 16 + fm];
        #pragma unroll
        for (int r_ = 0; r_ < 4; r_++) {
            int rl = rt * 16 + fq * 4 + r_;
            int row = i0 + rl;
            if (rl < 24 && row < n) out[(size_t)row * 32 + nc * 16 + fm] = acc[r_] + bias;
        }
    }
}

// ---- round-5 fallback (no workspace) ----
__global__ __launch_bounds__(256) void nnlstm_fallback(
    const float* __restrict__ obs1, const float* __restrict__ obs2,
    const float* __restrict__ h,    const float* __restrict__ c,
    const float* __restrict__ Wemb, const float* __restrict__ bemb,
    const float* __restrict__ Wih,  const float* __restrict__ bih,
    const float* __restrict__ Whh,  const float* __restrict__ bhh,
    const float* __restrict__ Wp,   const float* __restrict__ bp,
    int n, float* __restrict__ out)
{
    __shared__ float sMd[16][64];
    __shared__ int   sMj[16][64];
    __shared__ float sX[16][292];
    __shared__ float sH[16][264];

    const int t   = threadIdx.x;
    const int sub = t & 15;
    const int ii  = t >> 4;
    const int i0  = blockIdx.x * 16;
    const int i   = i0 + ii;

    for (int v = t; v < 16 * 256; v += 256) {
        int r = v >> 8, k = v & 255;
        int row = i0 + r;
        sX[r][32 + k] = (row < n) ? h[(size_t)row * 256 + k] : 0.0f;
    }

    float bd0 = 1e30f, bd1 = 1e30f, bd2 = 1e30f, bd3 = 1e30f;
    int   bj0 = 0x7fffffff, bj1 = 0x7fffffff, bj2 = 0x7fffffff, bj3 = 0x7fffffff;

    if (i < n) {
        const float pix = obs2[2 * i];
        const float piy = obs2[2 * i + 1];
        for (int j = sub; j < n; j += 16) {
            float dx = obs2[2 * j]     - pix;
            float dy = obs2[2 * j + 1] - piy;
            float d2 = __fadd_rn(__fmul_rn(dx, dx), __fmul_rn(dy, dy));
            float dist = __fsqrt_rn(d2);
            if (j == i) continue;
            INS4(dist, j);
        }
    }
    sMd[ii][sub * 4 + 0] = bd0;  sMj[ii][sub * 4 + 0] = bj0;
    sMd[ii][sub * 4 + 1] = bd1;  sMj[ii][sub * 4 + 1] = bj1;
    sMd[ii][sub * 4 + 2] = bd2;  sMj[ii][sub * 4 + 2] = bj2;
    sMd[ii][sub * 4 + 3] = bd3;  sMj[ii][sub * 4 + 3] = bj3;
    __syncthreads();

    if (t < 16) {
        const int r = t;
        const int irow = i0 + r;
        float bd0 = 1e30f, bd1 = 1e30f, bd2 = 1e30f, bd3 = 1e30f;
        int   bj0 = 0x7fffffff, bj1 = 0x7fffffff, bj2 = 0x7fffffff, bj3 = 0x7fffffff;
        for (int q = 0; q < 64; q++) { INS4(sMd[r][q], sMj[r][q]); }

        if (irow < n) {
            float pix = obs2[2 * irow], piy = obs2[2 * irow + 1];
            float vix = pix - obs1[2 * irow];
            float viy = piy - obs1[2 * irow + 1];
            #pragma unroll
            for (int q2 = 0; q2 < 4; q2++) {
                int jn = (q2 == 0) ? bj0 : (q2 == 1) ? bj1 : (q2 == 2) ? bj2 : bj3;
                if (jn < 0 || jn >= n) jn = 0;
                float pjx = obs2[2 * jn], pjy = obs2[2 * jn + 1];
                float px = pjx - pix, py = pjy - piy;
                float vx = (pjx - obs1[2 * jn])     - vix;
                float vy = (pjy - obs1[2 * jn + 1]) - viy;
                #pragma unroll
                for (int e = 0; e < 8; e++) {
                    float a = px * Wemb[e]      + py * Wemb[8 + e]
                            + vx * Wemb[16 + e] + vy * Wemb[24 + e]
                            + bemb[e];
                    sX[r][q2 * 8 + e] = fmaxf(a, 0.0f);
                }
            }
        } else {
            for (int e = 0; e < 32; e++) sX[r][e] = 0.0f;
        }
    }
    __syncthreads();

    const int uu = t;
    float acc[4][16];
    #pragma unroll
    for (int j = 0; j < 4; j++) {
        float b = bih[uu + 256 * j] + bhh[uu + 256 * j];
        #pragma unroll
        for (int r = 0; r < 16; r++) acc[j][r] = b;
    }

    for (int kc = 0; kc < 288; kc++) {
        float w[4];
        #pragma unroll
        for (int j = 0; j < 4; j++) {
            int g = uu + 256 * j;
            w[j] = (kc < 32) ? Wih[(size_t)g * 32 + kc]
                             : Whh[(size_t)g * 256 + (kc - 32)];
        }
        #pragma unroll
        for (int r = 0; r < 16; r++) {
            float x = sX[r][kc];
            #pragma unroll
            for (int j = 0; j < 4; j++) acc[j][r] += w[j] * x;
        }
    }

    for (int r = 0; r < 16; r++) {
        int row = i0 + r;
        float cin = (row < n) ? c[(size_t)row * 256 + uu] : 0.0f;
        float cn = sigf(acc[1][r]) * cin + sigf(acc[0][r]) * tanhf(acc[2][r]);
        float hn = sigf(acc[3][r]) * tanhf(cn);
        sH[r][uu] = hn;
    }
    __syncthreads();

    for (int v = t; v < 16 * 32; v += 256) {
        int r = v >> 5, o = v & 31;
        int row = i0 + r;
        if (row >= n) continue;
        float a = bp[o];
        for (int kc = 0; kc < 256; kc++)
            a += Wp[(size_t)o * 256 + kc] * sH[r][kc];
        out[(size_t)row * 32 + o] = a;
    }
}

extern "C" void kernel_launch(void* const* d_in, const int* in_sizes, int n_in,
                              void* d_out, int out_size, void* d_ws, size_t ws_size,
                              hipStream_t stream) {
    float* out = (float*)d_out;

    int code = 0, n = 0;
    if (n_in != 12) code = 1;
    else {
        n = in_sizes[1] / 2;
        if (n <= 4 || in_sizes[1] != 2 * n)          code = 2;
        else if (in_sizes[0]  != 2 * n)              code = 3;
        else if (in_sizes[2]  != 256 * n)            code = 4;
        else if (in_sizes[3]  != 256 * n)            code = 5;
        else if (in_sizes[4]  != 32 || in_sizes[5] != 8)        code = 6;
        else if (in_sizes[6]  != 32768 || in_sizes[7] != 1024)  code = 7;
        else if (in_sizes[8]  != 262144 || in_sizes[9] != 1024) code = 8;
        else if (in_sizes[10] != 8192 || in_sizes[11] != 32)    code = 9;
        else if (out_size != 32 * n)                 code = 10;
    }
    if (code != 0) {
        diag_kernel<<<1, 1, 0, stream>>>(out, code, out_size);
        return;
    }

    const float* obs1   = (const float*)d_in[0];
    const float* obs2   = (const float*)d_in[1];
    const float* h      = (const float*)d_in[2];
    const float* c      = (const float*)d_in[3];
    const float* W_emb  = (const float*)d_in[4];
    const float* b_emb  = (const float*)d_in[5];
    const float* W_ih   = (const float*)d_in[6];
    const float* b_ih   = (const float*)d_in[7];
    const float* W_hh   = (const float*)d_in[8];
    const float* b_hh   = (const float*)d_in[9];
    const float* W_pool = (const float*)d_in[10];
    const float* b_pool = (const float*)d_in[11];

    const size_t wgf_bytes = (size_t)36864 * 8 * sizeof(u16);   // 589,824
    const size_t wpf_bytes = (size_t)1024 * 8 * sizeof(u16);    //  16,384

    if (ws_size >= wgf_bytes + wpf_bytes && n <= (1 << 24)) {
        u16* Wgf = (u16*)d_ws;
        u16* Wpf = (u16*)((char*)d_ws + wgf_bytes);
        const size_t lds_bytes = (size_t)((n + 1) & ~1) * 8;    // pair-rounded
        if (lds_bytes <= 49152) {                               // n <= 6144: LDS path
            int knn_blocks = (n + 7) / 8;                       // 8 peds/block (8 waves)
            int prep_blocks = (37888 + 511) / 512;              // 74
            knn_prep_lds_kernel<<<knn_blocks + prep_blocks, 512, lds_bytes, stream>>>(
                obs1, obs2, W_emb, b_emb, W_ih, W_hh, W_pool, Wgf, Wpf,
                n, knn_blocks, out);
        } else {
            int knn_blocks = (n + 3) / 4;
            knn_prep_kernel<<<knn_blocks + 148, 256, 0, stream>>>(
                obs1, obs2, W_emb, b_emb, W_ih, W_hh, W_pool, Wgf, Wpf,
                n, knn_blocks, out);
        }
        lstm_kernel<<<(n + 23) / 24, 512, 0, stream>>>(
            h, c, Wgf, b_ih, b_hh, Wpf, b_pool, n, out);
    } else {
        nnlstm_fallback<<<(n + 15) / 16, 256, 0, stream>>>(
            obs1, obs2, h, c, W_emb, b_emb, W_ih, b_ih, W_hh, b_hh,
            W_pool, b_pool, n, out);
    }
}